// Round 1
// baseline (185.420 us; speedup 1.0000x reference)
//
#include <hip/hip_runtime.h>
#include <hip/hip_bf16.h>

#define B_N 32
#define SX 2048
#define SY 512
#define DIM 1024
#define NTOK 2
#define DN 128
#define ODIM 1024

#define BM 128
#define BK 64

typedef __bf16 bf16;
typedef __bf16 bf16x8 __attribute__((ext_vector_type(8)));
typedef __bf16 bf16x4 __attribute__((ext_vector_type(4)));
typedef float f32x4 __attribute__((ext_vector_type(4)));

__device__ __forceinline__ f32x4 mfma16(bf16x8 a, bf16x8 b, f32x4 c) {
  return __builtin_amdgcn_mfma_f32_16x16x32_bf16(a, b, c, 0, 0, 0);
}

// Convert weights fp32 -> bf16 once per call (weights are small, L2-resident).
__global__ __launch_bounds__(256) void prep_kernel(const float* __restrict__ Wd,
                                                   const float* __restrict__ Wu,
                                                   bf16* __restrict__ wdb,
                                                   bf16* __restrict__ wub) {
  int i = blockIdx.x * 256 + threadIdx.x;
  if (i < DN * DIM) {
    wdb[i] = (bf16)Wd[i];
    wub[i] = (bf16)Wu[i];
  }
}

// tokens[b,t,:] = latent[t] + sum_s softmax_s(latent[t].y[b,s]) * y[b,s]
// Only needed when gate != 0 (slow path; bench has gate == 0).
__global__ __launch_bounds__(256) void tokens_kernel(const float* __restrict__ y,
                                                     const float* __restrict__ lat,
                                                     const float* __restrict__ gate,
                                                     float* __restrict__ tokens) {
  if (gate[0] == 0.0f) return;  // output is independent of tokens in that case
  __shared__ float s_lat[NTOK][DIM];
  __shared__ float s_sc[NTOK][SY];
  int b = blockIdx.x;
  int tid = threadIdx.x, wave = tid >> 6, lane = tid & 63;
  const float* yb = y + (size_t)b * SY * DIM;
  for (int i = tid; i < NTOK * DIM; i += 256) ((float*)s_lat)[i] = lat[i];
  __syncthreads();
  // scores
  for (int s = wave * 128; s < wave * 128 + 128; ++s) {
    const float* yr = yb + (size_t)s * DIM;
    float d0 = 0.f, d1 = 0.f;
#pragma unroll
    for (int i = 0; i < 4; ++i) {
      f32x4 v = *(const f32x4*)(yr + lane * 4 + i * 256);
      f32x4 l0 = *(const f32x4*)(&s_lat[0][lane * 4 + i * 256]);
      f32x4 l1 = *(const f32x4*)(&s_lat[1][lane * 4 + i * 256]);
      d0 += v[0] * l0[0] + v[1] * l0[1] + v[2] * l0[2] + v[3] * l0[3];
      d1 += v[0] * l1[0] + v[1] * l1[1] + v[2] * l1[2] + v[3] * l1[3];
    }
#pragma unroll
    for (int off = 32; off > 0; off >>= 1) {
      d0 += __shfl_xor(d0, off);
      d1 += __shfl_xor(d1, off);
    }
    if (lane == 0) { s_sc[0][s] = d0; s_sc[1][s] = d1; }
  }
  __syncthreads();
  // softmax over s (wave 0 -> t=0, wave 1 -> t=1)
  if (wave < 2) {
    float m = -3.4e38f;
    for (int s = lane; s < SY; s += 64) m = fmaxf(m, s_sc[wave][s]);
#pragma unroll
    for (int off = 32; off > 0; off >>= 1) m = fmaxf(m, __shfl_xor(m, off));
    float sum = 0.f;
    for (int s = lane; s < SY; s += 64) {
      float e = expf(s_sc[wave][s] - m);
      s_sc[wave][s] = e;
      sum += e;
    }
#pragma unroll
    for (int off = 32; off > 0; off >>= 1) sum += __shfl_xor(sum, off);
    float inv = 1.f / sum;
    for (int s = lane; s < SY; s += 64) s_sc[wave][s] *= inv;
  }
  __syncthreads();
  // weighted sum over s
  float a0[4] = {0.f, 0.f, 0.f, 0.f}, a1[4] = {0.f, 0.f, 0.f, 0.f};
  for (int s = 0; s < SY; ++s) {
    float p0 = s_sc[0][s], p1 = s_sc[1][s];
    const float* yr = yb + (size_t)s * DIM;
#pragma unroll
    for (int i = 0; i < 4; ++i) {
      float v = yr[tid + i * 256];
      a0[i] += p0 * v;
      a1[i] += p1 * v;
    }
  }
  float* tb = tokens + (size_t)b * NTOK * DIM;
#pragma unroll
  for (int i = 0; i < 4; ++i) {
    tb[tid + i * 256] = s_lat[0][tid + i * 256] + a0[i];
    tb[DIM + tid + i * 256] = s_lat[1][tid + i * 256] + a1[i];
  }
}

// Fused: x' = x + gate*softmax_t(x.tok_t)*tok  ->  Z = relu(x' Wd^T) -> out = Z Wu^T
__global__ __launch_bounds__(256) void main_kernel(const float* __restrict__ x,
                                                   const float* __restrict__ gate,
                                                   const float* __restrict__ tokens,
                                                   const bf16* __restrict__ wdb,
                                                   const bf16* __restrict__ wub,
                                                   float* __restrict__ out) {
  __shared__ union {
    bf16 xs[BM][BK];   // 16 KB, XOR-swizzled
    bf16 zs[BM][DN];   // 32 KB, XOR-swizzled (aliases xs; barriered)
  } u;
  __shared__ float s_tok[NTOK][DIM];
  __shared__ float s_c[BM][2];

  int tid = threadIdx.x, wave = tid >> 6, lane = tid & 63;
  int wr = wave >> 1, wc = wave & 1;
  size_t m0 = (size_t)blockIdx.x * BM;
  int b = (int)(m0 / SX);
  const float* xb = x + m0 * DIM;
  float g = gate[0];

  const float* tokb = tokens + (size_t)b * NTOK * DIM;
  for (int i = tid; i < NTOK * DIM; i += 256) ((float*)s_tok)[i] = (g != 0.f) ? tokb[i] : 0.f;
  if (tid < BM) { s_c[tid][0] = 0.f; s_c[tid][1] = 0.f; }
  __syncthreads();

  if (g != 0.f) {
    // attention of x rows over the 2 tokens; fold gate & softmax into coeffs
    for (int r = wave * 32; r < wave * 32 + 32; ++r) {
      const float* xr = xb + (size_t)r * DIM;
      float d0 = 0.f, d1 = 0.f;
#pragma unroll
      for (int i = 0; i < 4; ++i) {
        f32x4 v = *(const f32x4*)(xr + lane * 4 + i * 256);
        f32x4 t0 = *(const f32x4*)(&s_tok[0][lane * 4 + i * 256]);
        f32x4 t1 = *(const f32x4*)(&s_tok[1][lane * 4 + i * 256]);
        d0 += v[0] * t0[0] + v[1] * t0[1] + v[2] * t0[2] + v[3] * t0[3];
        d1 += v[0] * t1[0] + v[1] * t1[1] + v[2] * t1[2] + v[3] * t1[3];
      }
#pragma unroll
      for (int off = 32; off > 0; off >>= 1) {
        d0 += __shfl_xor(d0, off);
        d1 += __shfl_xor(d1, off);
      }
      if (lane == 0) {
        float mm = fmaxf(d0, d1);
        float e0 = expf(d0 - mm), e1 = expf(d1 - mm);
        float inv = g / (e0 + e1);
        s_c[r][0] = e0 * inv;
        s_c[r][1] = e1 * inv;
      }
    }
    __syncthreads();
  }

  f32x4 acc1[4][4] = {};
  char* xsb = (char*)u.xs;

  // GEMM1: Z[128x128] = x'[128x1024] @ Wd^T
  for (int kc = 0; kc < DIM / BK; ++kc) {
    __syncthreads();
    // stage x' chunk -> bf16 LDS (swizzled)
#pragma unroll
    for (int it = 0; it < 8; ++it) {
      int idx = tid + it * 256;
      int row = idx >> 4;
      int c4 = idx & 15;
      int kbase = kc * BK + c4 * 4;
      f32x4 v = *(const f32x4*)(xb + (size_t)row * DIM + kbase);
      float c0 = s_c[row][0], c1 = s_c[row][1];
      f32x4 t0 = *(const f32x4*)(&s_tok[0][kbase]);
      f32x4 t1 = *(const f32x4*)(&s_tok[1][kbase]);
      bf16x4 o;
#pragma unroll
      for (int j = 0; j < 4; ++j) o[j] = (bf16)(v[j] + c0 * t0[j] + c1 * t1[j]);
      *(bf16x4*)(xsb + row * (BK * 2) + ((c4 * 8) ^ ((row & 7) << 4))) = o;
    }
    __syncthreads();
#pragma unroll
    for (int kk = 0; kk < BK; kk += 32) {
      int k = kk + (lane >> 4) * 8;
      bf16x8 a[4];
#pragma unroll
      for (int rt = 0; rt < 4; ++rt) {
        int r = wr * 64 + rt * 16 + (lane & 15);
        a[rt] = *(const bf16x8*)(xsb + r * (BK * 2) + ((2 * k) ^ ((r & 7) << 4)));
      }
      int kg = kc * BK + k;
#pragma unroll
      for (int nt = 0; nt < 4; ++nt) {
        int n = wc * 64 + nt * 16 + (lane & 15);
        bf16x8 bfr = *(const bf16x8*)(wdb + (size_t)n * DIM + kg);
#pragma unroll
        for (int rt = 0; rt < 4; ++rt) acc1[rt][nt] = mfma16(a[rt], bfr, acc1[rt][nt]);
      }
    }
  }

  // ReLU -> bf16 Z into LDS (aliases x-stage buffer)
  __syncthreads();
  char* zsb = (char*)u.zs;
#pragma unroll
  for (int rt = 0; rt < 4; ++rt) {
#pragma unroll
    for (int nt = 0; nt < 4; ++nt) {
      int col = wc * 64 + nt * 16 + (lane & 15);
#pragma unroll
      for (int reg = 0; reg < 4; ++reg) {
        int row = wr * 64 + rt * 16 + (lane >> 4) * 4 + reg;
        float zv = fmaxf(acc1[rt][nt][reg], 0.f);
        *(bf16*)(zsb + row * (DN * 2) + ((2 * col) ^ ((row & 7) << 4))) = (bf16)zv;
      }
    }
  }
  __syncthreads();

  // GEMM2: out[128x1024] = Z[128x128] @ Wu^T
  float* ob = out + m0 * ODIM;
  for (int nc = 0; nc < ODIM / 128; ++nc) {
    f32x4 acc2[4][4] = {};
#pragma unroll
    for (int kk = 0; kk < DN; kk += 32) {
      int k = kk + (lane >> 4) * 8;
      bf16x8 a[4];
#pragma unroll
      for (int rt = 0; rt < 4; ++rt) {
        int r = wr * 64 + rt * 16 + (lane & 15);
        a[rt] = *(const bf16x8*)(zsb + r * (DN * 2) + ((2 * k) ^ ((r & 7) << 4)));
      }
#pragma unroll
      for (int nt = 0; nt < 4; ++nt) {
        int n = nc * 128 + wc * 64 + nt * 16 + (lane & 15);
        bf16x8 bfr = *(const bf16x8*)(wub + (size_t)n * DN + k);
#pragma unroll
        for (int rt = 0; rt < 4; ++rt) acc2[rt][nt] = mfma16(a[rt], bfr, acc2[rt][nt]);
      }
    }
#pragma unroll
    for (int rt = 0; rt < 4; ++rt) {
      int row0 = wr * 64 + rt * 16 + (lane >> 4) * 4;
#pragma unroll
      for (int nt = 0; nt < 4; ++nt) {
        int col = nc * 128 + wc * 64 + nt * 16 + (lane & 15);
#pragma unroll
        for (int reg = 0; reg < 4; ++reg)
          ob[(size_t)(row0 + reg) * ODIM + col] = acc2[rt][nt][reg];
      }
    }
  }
}

extern "C" void kernel_launch(void* const* d_in, const int* in_sizes, int n_in,
                              void* d_out, int out_size, void* d_ws, size_t ws_size,
                              hipStream_t stream) {
  const float* x = (const float*)d_in[0];
  const float* y = (const float*)d_in[1];
  const float* lat = (const float*)d_in[2];
  const float* gate = (const float*)d_in[3];
  const float* Wd = (const float*)d_in[4];
  const float* Wu = (const float*)d_in[5];
  float* out = (float*)d_out;
  char* ws = (char*)d_ws;

  float* tokens = (float*)ws;              // 32*2*1024*4   = 262144 B
  bf16* wdb = (bf16*)(ws + 262144);        // 128*1024*2    = 262144 B
  bf16* wub = (bf16*)(ws + 524288);        // 1024*128*2    = 262144 B

  prep_kernel<<<(DN * DIM + 255) / 256, 256, 0, stream>>>(Wd, Wu, wdb, wub);
  tokens_kernel<<<B_N, 256, 0, stream>>>(y, lat, gate, tokens);
  main_kernel<<<(B_N * SX) / BM, 256, 0, stream>>>(x, gate, tokens, wdb, wub, out);
}

// Round 2
// 184.604 us; speedup vs baseline: 1.0044x; 1.0044x over previous
//
#include <hip/hip_runtime.h>
#include <hip/hip_bf16.h>

#define B_N 32
#define SX 2048
#define SY 512
#define DIM 1024
#define NTOK 2
#define DN 128
#define ODIM 1024

#define BM 64
#define BK 64

typedef __bf16 bf16;
typedef __bf16 bf16x8 __attribute__((ext_vector_type(8)));
typedef __bf16 bf16x4 __attribute__((ext_vector_type(4)));
typedef float f32x4 __attribute__((ext_vector_type(4)));

__device__ __forceinline__ f32x4 mfma16(bf16x8 a, bf16x8 b, f32x4 c) {
  return __builtin_amdgcn_mfma_f32_16x16x32_bf16(a, b, c, 0, 0, 0);
}

// Convert weights fp32 -> bf16 once per call (weights are small, L2-resident).
__global__ __launch_bounds__(256) void prep_kernel(const float* __restrict__ Wd,
                                                   const float* __restrict__ Wu,
                                                   bf16* __restrict__ wdb,
                                                   bf16* __restrict__ wub) {
  int i = blockIdx.x * 256 + threadIdx.x;
  if (i < DN * DIM) {
    wdb[i] = (bf16)Wd[i];
    wub[i] = (bf16)Wu[i];
  }
}

// tokens[b,t,:] = latent[t] + sum_s softmax_s(latent[t].y[b,s]) * y[b,s]
// Only needed when gate != 0 (slow path; bench has gate == 0).
__global__ __launch_bounds__(256) void tokens_kernel(const float* __restrict__ y,
                                                     const float* __restrict__ lat,
                                                     const float* __restrict__ gate,
                                                     float* __restrict__ tokens) {
  if (gate[0] == 0.0f) return;  // output is independent of tokens in that case
  __shared__ float s_lat[NTOK][DIM];
  __shared__ float s_sc[NTOK][SY];
  int b = blockIdx.x;
  int tid = threadIdx.x, wave = tid >> 6, lane = tid & 63;
  const float* yb = y + (size_t)b * SY * DIM;
  for (int i = tid; i < NTOK * DIM; i += 256) ((float*)s_lat)[i] = lat[i];
  __syncthreads();
  // scores
  for (int s = wave * 128; s < wave * 128 + 128; ++s) {
    const float* yr = yb + (size_t)s * DIM;
    float d0 = 0.f, d1 = 0.f;
#pragma unroll
    for (int i = 0; i < 4; ++i) {
      f32x4 v = *(const f32x4*)(yr + lane * 4 + i * 256);
      f32x4 l0 = *(const f32x4*)(&s_lat[0][lane * 4 + i * 256]);
      f32x4 l1 = *(const f32x4*)(&s_lat[1][lane * 4 + i * 256]);
      d0 += v[0] * l0[0] + v[1] * l0[1] + v[2] * l0[2] + v[3] * l0[3];
      d1 += v[0] * l1[0] + v[1] * l1[1] + v[2] * l1[2] + v[3] * l1[3];
    }
#pragma unroll
    for (int off = 32; off > 0; off >>= 1) {
      d0 += __shfl_xor(d0, off);
      d1 += __shfl_xor(d1, off);
    }
    if (lane == 0) { s_sc[0][s] = d0; s_sc[1][s] = d1; }
  }
  __syncthreads();
  // softmax over s (wave 0 -> t=0, wave 1 -> t=1)
  if (wave < 2) {
    float m = -3.4e38f;
    for (int s = lane; s < SY; s += 64) m = fmaxf(m, s_sc[wave][s]);
#pragma unroll
    for (int off = 32; off > 0; off >>= 1) m = fmaxf(m, __shfl_xor(m, off));
    float sum = 0.f;
    for (int s = lane; s < SY; s += 64) {
      float e = expf(s_sc[wave][s] - m);
      s_sc[wave][s] = e;
      sum += e;
    }
#pragma unroll
    for (int off = 32; off > 0; off >>= 1) sum += __shfl_xor(sum, off);
    float inv = 1.f / sum;
    for (int s = lane; s < SY; s += 64) s_sc[wave][s] *= inv;
  }
  __syncthreads();
  // weighted sum over s
  float a0[4] = {0.f, 0.f, 0.f, 0.f}, a1[4] = {0.f, 0.f, 0.f, 0.f};
  for (int s = 0; s < SY; ++s) {
    float p0 = s_sc[0][s], p1 = s_sc[1][s];
    const float* yr = yb + (size_t)s * DIM;
#pragma unroll
    for (int i = 0; i < 4; ++i) {
      float v = yr[tid + i * 256];
      a0[i] += p0 * v;
      a1[i] += p1 * v;
    }
  }
  float* tb = tokens + (size_t)b * NTOK * DIM;
#pragma unroll
  for (int i = 0; i < 4; ++i) {
    tb[tid + i * 256] = s_lat[0][tid + i * 256] + a0[i];
    tb[DIM + tid + i * 256] = s_lat[1][tid + i * 256] + a1[i];
  }
}

// Fused: x' = x + gate*softmax_t(x.tok_t)*tok  ->  Z = relu(x' Wd^T) -> out = Z Wu^T
// BM=64 rows/block, 1024 blocks, double-buffered LDS + register prefetch.
__global__ __launch_bounds__(256) void main_kernel(const float* __restrict__ x,
                                                   const float* __restrict__ gate,
                                                   const float* __restrict__ tokens,
                                                   const bf16* __restrict__ wdb,
                                                   const bf16* __restrict__ wub,
                                                   float* __restrict__ out) {
  __shared__ union {
    bf16 xs[2][BM][BK];  // 2 x 8 KB double buffer, XOR-swizzled
    bf16 zs[BM][DN];     // 16 KB, XOR-swizzled (aliases xs; barriered)
  } u;
  __shared__ float s_tok[NTOK][DIM];
  __shared__ float s_c[BM][2];

  int tid = threadIdx.x, wave = tid >> 6, lane = tid & 63;
  int wr = wave >> 1, wc = wave & 1;  // 2x2 wave grid; wave tile 32x64
  size_t m0 = (size_t)blockIdx.x * BM;
  int b = (int)(m0 / SX);
  const float* xb = x + m0 * DIM;
  float g = gate[0];

  if (g != 0.f) {
    const float* tokb = tokens + (size_t)b * NTOK * DIM;
    for (int i = tid; i < NTOK * DIM; i += 256) ((float*)s_tok)[i] = tokb[i];
    __syncthreads();
    // attention of x rows over the 2 tokens; fold gate & softmax into coeffs
    for (int r = wave * 16; r < wave * 16 + 16; ++r) {
      const float* xr = xb + (size_t)r * DIM;
      float d0 = 0.f, d1 = 0.f;
#pragma unroll
      for (int i = 0; i < 4; ++i) {
        f32x4 v = *(const f32x4*)(xr + lane * 4 + i * 256);
        f32x4 t0 = *(const f32x4*)(&s_tok[0][lane * 4 + i * 256]);
        f32x4 t1 = *(const f32x4*)(&s_tok[1][lane * 4 + i * 256]);
        d0 += v[0] * t0[0] + v[1] * t0[1] + v[2] * t0[2] + v[3] * t0[3];
        d1 += v[0] * t1[0] + v[1] * t1[1] + v[2] * t1[2] + v[3] * t1[3];
      }
#pragma unroll
      for (int off = 32; off > 0; off >>= 1) {
        d0 += __shfl_xor(d0, off);
        d1 += __shfl_xor(d1, off);
      }
      if (lane == 0) {
        float mm = fmaxf(d0, d1);
        float e0 = expf(d0 - mm), e1 = expf(d1 - mm);
        float inv = g / (e0 + e1);
        s_c[r][0] = e0 * inv;
        s_c[r][1] = e1 * inv;
      }
    }
    __syncthreads();
  }

  f32x4 acc1[2][4] = {};
  char* xsb = (char*)u.xs;

  // Prologue: prefetch chunk 0 into registers (4 x f32x4 per thread).
  int prow = tid >> 4;        // 0..15 per 256/16... rows 0..15 for it=0
  int pc4 = tid & 15;
  f32x4 pre[4];
#pragma unroll
  for (int it = 0; it < 4; ++it) {
    int row = prow + it * 16;
    pre[it] = *(const f32x4*)(xb + (size_t)row * DIM + pc4 * 4);
  }

  // GEMM1: Z[64x128] = x'[64x1024] @ Wd^T ; one barrier per K-step.
  for (int kc = 0; kc < DIM / BK; ++kc) {
    char* buf = xsb + (kc & 1) * (BM * BK * 2);
    // convert current prefetch -> bf16 LDS (swizzled)
    if (g != 0.f) {
      int kbase = kc * BK + pc4 * 4;
      f32x4 t0 = *(const f32x4*)(&s_tok[0][kbase]);
      f32x4 t1 = *(const f32x4*)(&s_tok[1][kbase]);
#pragma unroll
      for (int it = 0; it < 4; ++it) {
        int row = prow + it * 16;
        float c0 = s_c[row][0], c1 = s_c[row][1];
        bf16x4 o;
#pragma unroll
        for (int j = 0; j < 4; ++j) o[j] = (bf16)(pre[it][j] + c0 * t0[j] + c1 * t1[j]);
        *(bf16x4*)(buf + row * (BK * 2) + ((pc4 * 8) ^ ((row & 7) << 4))) = o;
      }
    } else {
#pragma unroll
      for (int it = 0; it < 4; ++it) {
        int row = prow + it * 16;
        bf16x4 o;
#pragma unroll
        for (int j = 0; j < 4; ++j) o[j] = (bf16)pre[it][j];
        *(bf16x4*)(buf + row * (BK * 2) + ((pc4 * 8) ^ ((row & 7) << 4))) = o;
      }
    }
    // issue next chunk's loads; they stay in flight across barrier + MFMA
    if (kc + 1 < DIM / BK) {
#pragma unroll
      for (int it = 0; it < 4; ++it) {
        int row = prow + it * 16;
        pre[it] = *(const f32x4*)(xb + (size_t)row * DIM + (kc + 1) * BK + pc4 * 4);
      }
    }
    __syncthreads();
#pragma unroll
    for (int kk = 0; kk < BK; kk += 32) {
      int k = kk + (lane >> 4) * 8;
      bf16x8 a[2];
#pragma unroll
      for (int rt = 0; rt < 2; ++rt) {
        int r = wr * 32 + rt * 16 + (lane & 15);
        a[rt] = *(const bf16x8*)(buf + r * (BK * 2) + ((2 * k) ^ ((r & 7) << 4)));
      }
      int kg = kc * BK + k;
#pragma unroll
      for (int nt = 0; nt < 4; ++nt) {
        int n = wc * 64 + nt * 16 + (lane & 15);
        bf16x8 bfr = *(const bf16x8*)(wdb + (size_t)n * DIM + kg);
#pragma unroll
        for (int rt = 0; rt < 2; ++rt) acc1[rt][nt] = mfma16(a[rt], bfr, acc1[rt][nt]);
      }
    }
    __syncthreads();  // all waves done with buf before it's overwritten (kc+2)
  }

  // ReLU -> bf16 Z into LDS (aliases x-stage buffers; barrier above protects)
  char* zsb = (char*)u.zs;
#pragma unroll
  for (int rt = 0; rt < 2; ++rt) {
#pragma unroll
    for (int nt = 0; nt < 4; ++nt) {
      int col = wc * 64 + nt * 16 + (lane & 15);
#pragma unroll
      for (int reg = 0; reg < 4; ++reg) {
        int row = wr * 32 + rt * 16 + (lane >> 4) * 4 + reg;
        float zv = fmaxf(acc1[rt][nt][reg], 0.f);
        *(bf16*)(zsb + row * (DN * 2) + ((2 * col) ^ ((row & 7) << 4))) = (bf16)zv;
      }
    }
  }
  __syncthreads();

  // GEMM2: out[64x1024] = Z[64x128] @ Wu^T
  float* ob = out + m0 * ODIM;
  for (int nc = 0; nc < ODIM / 128; ++nc) {
    f32x4 acc2[2][4] = {};
#pragma unroll
    for (int kk = 0; kk < DN; kk += 32) {
      int k = kk + (lane >> 4) * 8;
      bf16x8 a[2];
#pragma unroll
      for (int rt = 0; rt < 2; ++rt) {
        int r = wr * 32 + rt * 16 + (lane & 15);
        a[rt] = *(const bf16x8*)(zsb + r * (DN * 2) + ((2 * k) ^ ((r & 7) << 4)));
      }
#pragma unroll
      for (int nt = 0; nt < 4; ++nt) {
        int n = nc * 128 + wc * 64 + nt * 16 + (lane & 15);
        bf16x8 bfr = *(const bf16x8*)(wub + (size_t)n * DN + k);
#pragma unroll
        for (int rt = 0; rt < 2; ++rt) acc2[rt][nt] = mfma16(a[rt], bfr, acc2[rt][nt]);
      }
    }
#pragma unroll
    for (int rt = 0; rt < 2; ++rt) {
      int row0 = wr * 32 + rt * 16 + (lane >> 4) * 4;
#pragma unroll
      for (int nt = 0; nt < 4; ++nt) {
        int col = nc * 128 + wc * 64 + nt * 16 + (lane & 15);
#pragma unroll
        for (int reg = 0; reg < 4; ++reg)
          ob[(size_t)(row0 + reg) * ODIM + col] = acc2[rt][nt][reg];
      }
    }
  }
}

extern "C" void kernel_launch(void* const* d_in, const int* in_sizes, int n_in,
                              void* d_out, int out_size, void* d_ws, size_t ws_size,
                              hipStream_t stream) {
  const float* x = (const float*)d_in[0];
  const float* y = (const float*)d_in[1];
  const float* lat = (const float*)d_in[2];
  const float* gate = (const float*)d_in[3];
  const float* Wd = (const float*)d_in[4];
  const float* Wu = (const float*)d_in[5];
  float* out = (float*)d_out;
  char* ws = (char*)d_ws;

  float* tokens = (float*)ws;              // 32*2*1024*4   = 262144 B
  bf16* wdb = (bf16*)(ws + 262144);        // 128*1024*2    = 262144 B
  bf16* wub = (bf16*)(ws + 524288);        // 1024*128*2    = 262144 B

  prep_kernel<<<(DN * DIM + 255) / 256, 256, 0, stream>>>(Wd, Wu, wdb, wub);
  tokens_kernel<<<B_N, 256, 0, stream>>>(y, lat, gate, tokens);
  main_kernel<<<(B_N * SX) / BM, 256, 0, stream>>>(x, gate, tokens, wdb, wub, out);
}